// Round 2
// baseline (302.675 us; speedup 1.0000x reference)
//
#include <hip/hip_runtime.h>

// TTN Conv: out[n,p,o,site] = sum_{c,i,j,k,l} a_i b_j c_k d_l * W[c,p,site,ijkl,o] + bias
// Per site: GEMM D[n=128][po=48] = sum_k A[n][k=768] * W[k][po], bf16 MFMA 16x16x32.
//
// x:       (128, 3, 4, 32, 32) fp32
// tensors: (3, 8, 31, 31, 256, 6) fp32  -> per (c,p,site): [m=256][o=6] contiguous
// bias:    (8, 31, 31, 6) fp32
// out:     (128, 8, 6, 31, 31) fp32 = out[f*961 + site], f = n*48 + p*6 + o
//
// R3 structure (A-in-registers, sW double-buffer, 2-deep W prefetch, no vmcnt
// drain at barriers). R4 fixes R3's race: __builtin_amdgcn_s_barrier() is
// IntrNoMem -- NOT a compiler memory fence -- so plain LDS fragment reads were
// hoisted above the barrier (ch=0: uninitialized LDS -> NaN). Fix: fuse
// "s_waitcnt lgkmcnt(0); s_barrier" into ONE asm volatile with "memory"
// clobber (no LDS op can cross), + sched_barrier(0) after (rule #18).
// Also: b_[mt][j] runtime-indexed local -> scratch (rule #20); replaced with
// explicit cndmask selection at x-load time (bsel[nn][ks]).
//
//  * A-fragments built IN REGISTERS: lane (row,quad) computes its own 8 A values
//      A[n][ks*32+quad*8+e] = a[mb] * b[ks*2+(quad>>1)] * cd[(quad&1)*8+e]
//    from per-lane x scalars for its 2 n-rows. No sA, no second barrier.
//  * sW double-buffered (2 x 6.9 KB); ONE fused barrier per chunk, lgkm drain
//    only -- global W prefetch stays in flight across barriers (T3/T4).
//    Safety: chunk ch stages buf=ch&1; compute(ch) readers of that buf are
//    lgkm-drained at barrier(ch+1), which precedes stage(ch+2) for every wave.
//  * W prefetch 2 chunks deep in 2 register sets (gap ~2 chunk periods).
//  * v_cvt_pk_bf16_f32 packs pairs along k for BOTH A and W operands, so the
//    lo/hi convention cancels in the dot product.
// Phase 2: tiled transpose ws(961 x 6144) -> out(6144 x 961) + bias (unchanged).

typedef __attribute__((ext_vector_type(8))) short short8;
typedef __attribute__((ext_vector_type(4))) float floatx4;

#define WS_ELEMS (961u * 6144u)
#define SW_STR 72           // 64+8 shorts: granule shift -> 2-way max on b128 reads (free)
#define C_STRIDE 11808768   // 8*961*1536 floats between c panels

static __device__ __forceinline__ unsigned cvt_pk_bf16(float lo, float hi) {
  unsigned r;
  asm("v_cvt_pk_bf16_f32 %0, %1, %2" : "=v"(r) : "v"(lo), "v"(hi));
  return r;
}

// lgkm drain + workgroup barrier as ONE volatile asm with memory clobber:
// compiler may not move any memory op across it; vmcnt left untouched so
// global prefetch loads stay in flight.
static __device__ __forceinline__ void barrier_lgkm() {
  asm volatile("s_waitcnt lgkmcnt(0)\n\ts_barrier" ::: "memory");
  __builtin_amdgcn_sched_barrier(0);
}

template <bool TO_WS>
__global__ __launch_bounds__(256, 4)
void ttn_conv_mfma(const float* __restrict__ x,
                   const float* __restrict__ tensors,
                   const float* __restrict__ bias,
                   float* __restrict__ dst) {
  __shared__ __align__(16) unsigned short sW[2][48 * SW_STR];  // 2 x 6912 B

  const int site = blockIdx.x;
  const int xx = site / 31, yy = site - xx * 31;
  const int t = threadIdx.x;
  const int lane = t & 63, wave = t >> 6;
  const int row = lane & 15, quad = lane >> 4;
  const int p_st = t >> 5;        // sW staging: p (0..7)
  const int q_st = t & 31;        // sW staging: m-pair index (m = 2q, 2q+1)
  const int k0 = (quad & 1) * 2;  // this lane's c_k index base (kl = (quad&1)*8 + e)

  floatx4 acc[2][3];
#pragma unroll
  for (int i0 = 0; i0 < 2; ++i0)
#pragma unroll
    for (int j0 = 0; j0 < 3; ++j0)
      acc[i0][j0] = (floatx4){0.f, 0.f, 0.f, 0.f};

  // per-lane x factors for the two n-rows this lane feeds (mt = 0,1)
  float a_[2][4];        // a_i (constant-indexed only: mb is unroll-constant)
  float bsel[2][2];      // b_{ks*2 + (quad>>1)} pre-selected per K-step
  float cd_[2][8];       // c_{k0 + (e>>2)} * d_{e&3}

  const float* wbase = tensors + ((size_t)(p_st * 961 + site)) * 1536 + 12 * q_st;

  // W prefetch register sets: set A holds even chunks, set B odd chunks.
  float4 wa0, wa1, wa2, wb0, wb1, wb2;
  wa0 = *(const float4*)(wbase + 0);      // chunk 0 (c=0, mb=0)
  wa1 = *(const float4*)(wbase + 4);
  wa2 = *(const float4*)(wbase + 8);
  wb0 = *(const float4*)(wbase + 384);    // chunk 1 (c=0, mb=1)
  wb1 = *(const float4*)(wbase + 388);
  wb2 = *(const float4*)(wbase + 392);

#pragma unroll
  for (int ch = 0; ch < 12; ++ch) {
    const int mb = ch & 3;

    if (mb == 0) {
      // x factors for c = ch>>2, both n-rows. Scalar loads (4B-aligned only).
      const int c = ch >> 2;
#pragma unroll
      for (int nn = 0; nn < 2; ++nn) {
        const int n = wave * 32 + nn * 16 + row;
        const float* xp = x + ((size_t)n * 3 + c) * 4096 + xx * 32 + yy;
        float bq[4], dq[4];
#pragma unroll
        for (int i = 0; i < 4; ++i) {
          const float* r0 = xp + i * 1024;
          a_[nn][i] = r0[0];    // a_i = x[n,c,i,xx,  yy  ]
          bq[i]     = r0[32];   // b_i = x[n,c,i,xx+1,yy  ]
          dq[i]     = r0[33];   // d_i = x[n,c,i,xx+1,yy+1]
        }
        // explicit select (v_cndmask), NOT runtime array index (rule #20)
        bsel[nn][0] = (quad & 2) ? bq[1] : bq[0];
        bsel[nn][1] = (quad & 2) ? bq[3] : bq[2];
        const float cq0 = xp[k0 * 1024 + 1];        // c_{k0}   = x[n,c,k0,  xx,yy+1]
        const float cq1 = xp[(k0 + 1) * 1024 + 1];  // c_{k0+1}
#pragma unroll
        for (int l = 0; l < 4; ++l) {
          cd_[nn][l]     = cq0 * dq[l];
          cd_[nn][4 + l] = cq1 * dq[l];
        }
      }
    }

    // ---- stage sW[ch&1][po][m_local] from this chunk's register set ----
    {
      const float4 w0 = (ch & 1) ? wb0 : wa0;
      const float4 w1 = (ch & 1) ? wb1 : wa1;
      const float4 w2 = (ch & 1) ? wb2 : wa2;
      const float vv[12] = {w0.x, w0.y, w0.z, w0.w, w1.x, w1.y,
                            w1.z, w1.w, w2.x, w2.y, w2.z, w2.w};
      unsigned short* dW = &sW[ch & 1][0];
#pragma unroll
      for (int o = 0; o < 6; ++o)
        *(unsigned*)&dW[(p_st * 6 + o) * SW_STR + 2 * q_st] =
            cvt_pk_bf16(vv[o], vv[o + 6]);
    }

    // ---- prefetch chunk ch+2 into the set just consumed (stays in flight
    //      across the fused barrier below -- vmcnt untouched) ----
    if (ch + 2 < 12) {
      const float* src =
          wbase + (size_t)((ch + 2) >> 2) * C_STRIDE + ((ch + 2) & 3) * 384;
      const float4 n0 = *(const float4*)src;
      const float4 n1 = *(const float4*)(src + 4);
      const float4 n2 = *(const float4*)(src + 8);
      if (ch & 1) { wb0 = n0; wb1 = n1; wb2 = n2; }
      else        { wa0 = n0; wa1 = n1; wa2 = n2; }
    }

    // One fused barrier per chunk: LDS writes drained + barrier, compiler
    // memory fence both directions; global loads left in flight.
    barrier_lgkm();

    // ---- compute: 2 K-steps of 32, wave tile 2(M) x 3(N), A built in regs ----
#pragma unroll
    for (int ks = 0; ks < 2; ++ks) {
      short8 af[2], bf[3];
#pragma unroll
      for (int mt = 0; mt < 2; ++mt) {
        const float ab = a_[mt][mb] * bsel[mt][ks];
        union { unsigned u[4]; short8 s; } pk;
        pk.u[0] = cvt_pk_bf16(ab * cd_[mt][0], ab * cd_[mt][1]);
        pk.u[1] = cvt_pk_bf16(ab * cd_[mt][2], ab * cd_[mt][3]);
        pk.u[2] = cvt_pk_bf16(ab * cd_[mt][4], ab * cd_[mt][5]);
        pk.u[3] = cvt_pk_bf16(ab * cd_[mt][6], ab * cd_[mt][7]);
        af[mt] = pk.s;
      }
      const int kof = ks * 32 + quad * 8;
#pragma unroll
      for (int nt = 0; nt < 3; ++nt)
        bf[nt] = *(const short8*)&sW[ch & 1][(nt * 16 + row) * SW_STR + kof];
#pragma unroll
      for (int mt = 0; mt < 2; ++mt)
#pragma unroll
        for (int nt = 0; nt < 3; ++nt)
          acc[mt][nt] = __builtin_amdgcn_mfma_f32_16x16x32_bf16(
              af[mt], bf[nt], acc[mt][nt], 0, 0, 0);
    }
    // No trailing barrier: next chunk stages the OTHER buffer; the chunk-(ch+1)
    // barrier orders this chunk's readers vs chunk-(ch+2)'s writers.
  }

  // ---- epilogue: D row = quad*4+r (n-local), col = lane&15 (po-local) ----
  if (TO_WS) {
#pragma unroll
    for (int mt = 0; mt < 2; ++mt)
#pragma unroll
      for (int r = 0; r < 4; ++r) {
        const int n = wave * 32 + mt * 16 + quad * 4 + r;
#pragma unroll
        for (int nt = 0; nt < 3; ++nt) {
          const int po = nt * 16 + row;
          dst[(size_t)site * 6144 + n * 48 + po] = acc[mt][nt][r];
        }
      }
  } else {
#pragma unroll
    for (int mt = 0; mt < 2; ++mt)
#pragma unroll
      for (int r = 0; r < 4; ++r) {
        const int n = wave * 32 + mt * 16 + quad * 4 + r;
#pragma unroll
        for (int nt = 0; nt < 3; ++nt) {
          const int po = nt * 16 + row;
          const int p = po / 6, o = po - p * 6;
          dst[(size_t)(n * 48 + po) * 961 + site] =
              acc[mt][nt][r] + bias[(p * 961 + site) * 6 + o];
        }
      }
  }
}

// out[f*961 + site] = ws[site*6144 + f] + bias[(p*961+site)*6 + o],  f = n*48+p*6+o
__global__ __launch_bounds__(256, 8)
void ttn_transpose_bias(const float* __restrict__ ws,
                        const float* __restrict__ bias,
                        float* __restrict__ out) {
  __shared__ float tile[32][33];
  const int f0 = blockIdx.x * 32;
  const int s0 = blockIdx.y * 32;
  const int tx = threadIdx.x;       // 0..31
  const int ty = threadIdx.y;       // 0..7

#pragma unroll
  for (int rr = 0; rr < 4; ++rr) {
    const int srow = ty + rr * 8;
    const int site = s0 + srow;
    if (site < 961)
      tile[srow][tx] = ws[(size_t)site * 6144 + f0 + tx];
  }
  __syncthreads();

#pragma unroll
  for (int rr = 0; rr < 4; ++rr) {
    const int fy = ty + rr * 8;
    const int f = f0 + fy;
    const int site = s0 + tx;
    if (site < 961) {
      const int po = f % 48;
      const int p = po / 6, o = po - p * 6;
      out[(size_t)f * 961 + site] = tile[tx][fy] + bias[(p * 961 + site) * 6 + o];
    }
  }
}

extern "C" void kernel_launch(void* const* d_in, const int* in_sizes, int n_in,
                              void* d_out, int out_size, void* d_ws, size_t ws_size,
                              hipStream_t stream) {
  const float* x       = (const float*)d_in[0];
  const float* tensors = (const float*)d_in[1];
  const float* bias    = (const float*)d_in[2];
  float* out           = (float*)d_out;

  const size_t need = (size_t)WS_ELEMS * sizeof(float);
  if (d_ws != nullptr && ws_size >= need) {
    float* ws = (float*)d_ws;
    hipLaunchKernelGGL((ttn_conv_mfma<true>), dim3(961), dim3(256), 0, stream,
                       x, tensors, bias, ws);
    hipLaunchKernelGGL(ttn_transpose_bias, dim3(192, 31), dim3(32, 8), 0, stream,
                       ws, bias, out);
  } else {
    hipLaunchKernelGGL((ttn_conv_mfma<false>), dim3(961), dim3(256), 0, stream,
                       x, tensors, bias, out);
  }
}